// Round 1
// baseline (14774.197 us; speedup 1.0000x reference)
//
#include <hip/hip_runtime.h>

#define D 128
#define NT 10   // edge types
#define NL 4    // layers
#define BN 128  // nodes per gemm block

// ---------------------------------------------------------------------------
// h = relu(x @ W1.T + b1) for the two K=2 input MLPs (fused)
// ---------------------------------------------------------------------------
__global__ void input_hidden_kernel(const float* __restrict__ ctrs,
                                    const float* __restrict__ feats,
                                    const float* __restrict__ inW1,
                                    const float* __restrict__ inb1,
                                    const float* __restrict__ segW1,
                                    const float* __restrict__ segb1,
                                    float* __restrict__ h_in,
                                    float* __restrict__ h_seg, int N) {
    int gid = blockIdx.x * blockDim.x + threadIdx.x;
    int n = gid >> 5;   // 32 threads/node
    int c = gid & 31;   // 4 outputs each
    if (n >= N) return;
    float x0 = ctrs[2 * n], x1 = ctrs[2 * n + 1];
    float y0 = feats[2 * n], y1 = feats[2 * n + 1];
    int o0 = c * 4;
    float hi[4], hs[4];
#pragma unroll
    for (int j = 0; j < 4; ++j) {
        int o = o0 + j;
        float a = fmaf(x0, inW1[2 * o], fmaf(x1, inW1[2 * o + 1], inb1[o]));
        hi[j] = fmaxf(a, 0.f);
        float b = fmaf(y0, segW1[2 * o], fmaf(y1, segW1[2 * o + 1], segb1[o]));
        hs[j] = fmaxf(b, 0.f);
    }
    *(float4*)&h_in[(size_t)n * D + o0] = make_float4(hi[0], hi[1], hi[2], hi[3]);
    *(float4*)&h_seg[(size_t)n * D + o0] = make_float4(hs[0], hs[1], hs[2], hs[3]);
}

// ---------------------------------------------------------------------------
// out[n][o] = act( sum_k A[n][k]*W[o*ldw+k] (+bias[o]) (+addin[n][o]) )
// A:[N][128], W row-major with leading dim ldw. 128 nodes x 128 outs / block.
// Thread: 8 nodes x 8 outs. LDS staged, transposed A tile for bank-friendly reads.
// ---------------------------------------------------------------------------
template <int BIAS, int RELU, int ADDIN>
__global__ __launch_bounds__(256) void gemm128_kernel(
    const float* __restrict__ A, const float* __restrict__ W,
    const float* __restrict__ bias, const float* addin, float* out, int N,
    int ldw) {
    __shared__ float xs[32][BN + 8];  // xs[k][n], pad 136: conflict-free b128 reads
    __shared__ float wt[32][D + 4];   // wt[k][o], pad 132
    int t = threadIdx.x;
    int n0 = blockIdx.x * BN;
    int tn = t >> 4;  // node group (8 nodes)
    int to = t & 15;  // out group (8 outs)
    float acc[8][8];
#pragma unroll
    for (int j = 0; j < 8; ++j)
#pragma unroll
        for (int m = 0; m < 8; ++m) acc[j][m] = 0.f;

    for (int kc = 0; kc < 4; ++kc) {
        int k0 = kc * 32;
        // A tile: 128 rows x 32 k -> 4 float4 per thread, written transposed
#pragma unroll
        for (int i = 0; i < 4; ++i) {
            int f4 = i * 256 + t;
            int row = f4 >> 3;
            int c4 = f4 & 7;
            int n = n0 + row;
            float4 v = make_float4(0.f, 0.f, 0.f, 0.f);
            if (n < N) v = *(const float4*)&A[(size_t)n * D + k0 + c4 * 4];
            xs[c4 * 4 + 0][row] = v.x;
            xs[c4 * 4 + 1][row] = v.y;
            xs[c4 * 4 + 2][row] = v.z;
            xs[c4 * 4 + 3][row] = v.w;
        }
        // W tile: 128 outs x 32 k, transposed to wt[k][o]
#pragma unroll
        for (int i = 0; i < 4; ++i) {
            int f4 = i * 256 + t;
            int o = f4 >> 3;
            int c4 = f4 & 7;
            float4 v = *(const float4*)&W[(size_t)o * ldw + k0 + c4 * 4];
            wt[c4 * 4 + 0][o] = v.x;
            wt[c4 * 4 + 1][o] = v.y;
            wt[c4 * 4 + 2][o] = v.z;
            wt[c4 * 4 + 3][o] = v.w;
        }
        __syncthreads();
#pragma unroll
        for (int kk = 0; kk < 32; ++kk) {
            float4 xa = *(const float4*)&xs[kk][tn * 8];
            float4 xb = *(const float4*)&xs[kk][tn * 8 + 4];
            float4 wa = *(const float4*)&wt[kk][to * 8];
            float4 wb = *(const float4*)&wt[kk][to * 8 + 4];
            float xr[8] = {xa.x, xa.y, xa.z, xa.w, xb.x, xb.y, xb.z, xb.w};
            float wr[8] = {wa.x, wa.y, wa.z, wa.w, wb.x, wb.y, wb.z, wb.w};
#pragma unroll
            for (int j = 0; j < 8; ++j)
#pragma unroll
                for (int m = 0; m < 8; ++m)
                    acc[j][m] = fmaf(xr[j], wr[m], acc[j][m]);
        }
        __syncthreads();
    }
    int o0 = to * 8;
    float bv[8] = {0, 0, 0, 0, 0, 0, 0, 0};
    if (BIAS) {
        float4 ba = *(const float4*)&bias[o0];
        float4 bb = *(const float4*)&bias[o0 + 4];
        bv[0] = ba.x; bv[1] = ba.y; bv[2] = ba.z; bv[3] = ba.w;
        bv[4] = bb.x; bv[5] = bb.y; bv[6] = bb.z; bv[7] = bb.w;
    }
#pragma unroll
    for (int j = 0; j < 8; ++j) {
        int n = n0 + tn * 8 + j;
        if (n < N) {
            float r[8];
#pragma unroll
            for (int m = 0; m < 8; ++m) r[m] = acc[j][m] + (BIAS ? bv[m] : 0.f);
            if (ADDIN) {
                float4 aa = *(const float4*)&addin[(size_t)n * D + o0];
                float4 ab = *(const float4*)&addin[(size_t)n * D + o0 + 4];
                r[0] += aa.x; r[1] += aa.y; r[2] += aa.z; r[3] += aa.w;
                r[4] += ab.x; r[5] += ab.y; r[6] += ab.z; r[7] += ab.w;
            }
            if (RELU) {
#pragma unroll
                for (int m = 0; m < 8; ++m) r[m] = fmaxf(r[m], 0.f);
            }
            *(float4*)&out[(size_t)n * D + o0] = make_float4(r[0], r[1], r[2], r[3]);
            *(float4*)&out[(size_t)n * D + o0 + 4] = make_float4(r[4], r[5], r[6], r[7]);
        }
    }
}

// ---------------------------------------------------------------------------
// temp[u[e]][:] += Y[v[e]][:]   (HW fp32 atomics, 512B-contiguous per edge)
// ---------------------------------------------------------------------------
__global__ void scatter_add_kernel(const float* __restrict__ Y,
                                   const int* __restrict__ eu,
                                   const int* __restrict__ ev, float* temp,
                                   int E) {
    int gid = blockIdx.x * blockDim.x + threadIdx.x;
    int e = gid >> 5;
    int c = gid & 31;
    if (e >= E) return;
    int u = eu[e], v = ev[e];
    float4 m = *(const float4*)&Y[(size_t)v * D + c * 4];
    float* dst = &temp[(size_t)u * D + c * 4];
    unsafeAtomicAdd(dst + 0, m.x);
    unsafeAtomicAdd(dst + 1, m.y);
    unsafeAtomicAdd(dst + 2, m.z);
    unsafeAtomicAdd(dst + 3, m.w);
}

// ---------------------------------------------------------------------------
// in-place GroupNorm(1,D) + affine + relu, one wave per node
// ---------------------------------------------------------------------------
__global__ __launch_bounds__(256) void norm_relu_kernel(float* temp,
                                                        const float* __restrict__ g,
                                                        const float* __restrict__ b,
                                                        int N) {
    int wid = (int)((blockIdx.x * (size_t)blockDim.x + threadIdx.x) >> 6);
    int lane = threadIdx.x & 63;
    if (wid >= N) return;
    float2 x = *(float2*)&temp[(size_t)wid * D + lane * 2];
    float s = x.x + x.y;
    float sq = x.x * x.x + x.y * x.y;
#pragma unroll
    for (int off = 32; off; off >>= 1) {
        s += __shfl_xor(s, off);
        sq += __shfl_xor(sq, off);
    }
    float mu = s * (1.f / 128.f);
    float var = sq * (1.f / 128.f) - mu * mu;
    float rs = rsqrtf(var + 1e-5f);
    float r0 = fmaxf(fmaf((x.x - mu) * rs, g[lane * 2], b[lane * 2]), 0.f);
    float r1 = fmaxf(fmaf((x.y - mu) * rs, g[lane * 2 + 1], b[lane * 2 + 1]), 0.f);
    *(float2*)&temp[(size_t)wid * D + lane * 2] = make_float2(r0, r1);
}

// ---------------------------------------------------------------------------
// mbuf[n][:] = embed[mark_type[n]][:]
// ---------------------------------------------------------------------------
__global__ void gather_meta_kernel(const int* __restrict__ mark,
                                   const float* __restrict__ embed, float* out,
                                   int N) {
    int gid = blockIdx.x * blockDim.x + threadIdx.x;
    int n = gid >> 5;
    int c = gid & 31;
    if (n >= N) return;
    *(float4*)&out[(size_t)n * D + c * 4] =
        *(const float4*)&embed[(size_t)mark[n] * D + c * 4];
}

// ---------------------------------------------------------------------------
static inline void launch_gemm(const float* A, const float* W, const float* bias,
                               const float* addin, float* out, int N, int ldw,
                               bool relu, hipStream_t s) {
    dim3 grid((N + BN - 1) / BN), blk(256);
    bool B = bias != nullptr, AD = addin != nullptr;
    if (B && !relu && !AD)
        gemm128_kernel<1, 0, 0><<<grid, blk, 0, s>>>(A, W, bias, addin, out, N, ldw);
    else if (B && relu && AD)
        gemm128_kernel<1, 1, 1><<<grid, blk, 0, s>>>(A, W, bias, addin, out, N, ldw);
    else if (!B && !relu && !AD)
        gemm128_kernel<0, 0, 0><<<grid, blk, 0, s>>>(A, W, bias, addin, out, N, ldw);
    else if (B && relu && !AD)
        gemm128_kernel<1, 1, 0><<<grid, blk, 0, s>>>(A, W, bias, addin, out, N, ldw);
    else if (!B && relu && AD)
        gemm128_kernel<0, 1, 1><<<grid, blk, 0, s>>>(A, W, bias, addin, out, N, ldw);
    else if (!B && relu && !AD)
        gemm128_kernel<0, 1, 0><<<grid, blk, 0, s>>>(A, W, bias, addin, out, N, ldw);
    else if (!B && !relu && AD)
        gemm128_kernel<0, 0, 1><<<grid, blk, 0, s>>>(A, W, bias, addin, out, N, ldw);
    else
        gemm128_kernel<1, 0, 1><<<grid, blk, 0, s>>>(A, W, bias, addin, out, N, ldw);
}

extern "C" void kernel_launch(void* const* d_in, const int* in_sizes, int n_in,
                              void* d_out, int out_size, void* d_ws,
                              size_t ws_size, hipStream_t stream) {
    const float* ctrs = (const float*)d_in[0];
    const float* feats = (const float*)d_in[1];
    const float* in_W1 = (const float*)d_in[2];
    const float* in_b1 = (const float*)d_in[3];
    const float* in_W2 = (const float*)d_in[4];
    const float* in_b2 = (const float*)d_in[5];
    const float* seg_W1 = (const float*)d_in[6];
    const float* seg_b1 = (const float*)d_in[7];
    const float* seg_W2 = (const float*)d_in[8];
    const float* seg_b2 = (const float*)d_in[9];
    const float* embed = (const float*)d_in[10];
    const float* meta_W1 = (const float*)d_in[11];
    const float* meta_b1 = (const float*)d_in[12];
    const float* meta_W2 = (const float*)d_in[13];
    const float* meta_b2 = (const float*)d_in[14];
    const float* ctr_W = (const float*)d_in[15];
    const float* edge_W = (const float*)d_in[16];
    const float* norm_g = (const float*)d_in[17];
    const float* norm_b = (const float*)d_in[18];
    const float* ctr2_W1 = (const float*)d_in[19];
    const float* ctr2_b1 = (const float*)d_in[20];
    const float* ctr2_W2 = (const float*)d_in[21];
    const float* ctr2_b2 = (const float*)d_in[22];
    const int* mark_type = (const int*)d_in[23];
    const int* edge_u = (const int*)d_in[24];
    const int* edge_v = (const int*)d_in[25];

    const int N = in_sizes[0] / 2;
    const int E = in_sizes[24] / NT;
    const size_t ND = (size_t)N * D;

    float* F = (float*)d_ws;        // feat / residual
    float* T1 = (float*)d_ws + ND;  // temp
    float* SC = (float*)d_out;      // scratch: Y / hidden / meta (overwritten at end)

    dim3 blk(256);
    dim3 g32((N * 32 + 255) / 256);
    dim3 g64(((size_t)N * 64 + 255) / 256);
    dim3 gE((E * 32 + 255) / 256);

    // ---- input stage: feat = relu(mlp(ctrs) + mlp(feats)) ----
    input_hidden_kernel<<<g32, blk, 0, stream>>>(ctrs, feats, in_W1, in_b1,
                                                 seg_W1, seg_b1, T1, SC, N);
    launch_gemm(T1, in_W2, in_b2, nullptr, F, N, D, false, stream);
    launch_gemm(SC, seg_W2, seg_b2, F, F, N, D, true, stream);

    // ---- fuse layers ----
    for (int i = 0; i < NL; ++i) {
        launch_gemm(F, ctr_W + (size_t)i * D * D, nullptr, nullptr, T1, N, D,
                    false, stream);
        for (int t = 0; t < NT; ++t) {
            launch_gemm(F, edge_W + ((size_t)i * NT + t) * D * D, nullptr,
                        nullptr, SC, N, D, false, stream);
            scatter_add_kernel<<<gE, blk, 0, stream>>>(
                SC, edge_u + (size_t)t * E, edge_v + (size_t)t * E, T1, E);
        }
        norm_relu_kernel<<<g64, blk, 0, stream>>>(T1, norm_g + (size_t)i * D,
                                                  norm_b + (size_t)i * D, N);
        launch_gemm(T1, ctr2_W1 + (size_t)i * D * D, ctr2_b1 + (size_t)i * D,
                    nullptr, SC, N, D, true, stream);
        launch_gemm(SC, ctr2_W2 + (size_t)i * D * D, ctr2_b2 + (size_t)i * D, F,
                    F, N, D, true, stream);
    }

    // ---- meta stage ----
    gather_meta_kernel<<<g32, blk, 0, stream>>>(mark_type, embed, SC, N);
    launch_gemm(F, meta_W1, meta_b1, nullptr, T1, N, 2 * D, false, stream);
    launch_gemm(SC, meta_W1 + D, nullptr, T1, T1, N, 2 * D, true, stream);
    launch_gemm(T1, meta_W2, meta_b2, nullptr, (float*)d_out, N, D, false,
                stream);
}

// Round 2
// 6520.543 us; speedup vs baseline: 2.2658x; 2.2658x over previous
//
#include <hip/hip_runtime.h>

#define D 128
#define NT 10   // edge types
#define NL 4    // layers
#define BN 128  // nodes per gemm block

// ---------------------------------------------------------------------------
// h = relu(x @ W1.T + b1) for the two K=2 input MLPs (fused)
// ---------------------------------------------------------------------------
__global__ void input_hidden_kernel(const float* __restrict__ ctrs,
                                    const float* __restrict__ feats,
                                    const float* __restrict__ inW1,
                                    const float* __restrict__ inb1,
                                    const float* __restrict__ segW1,
                                    const float* __restrict__ segb1,
                                    float* __restrict__ h_in,
                                    float* __restrict__ h_seg, int N) {
    int gid = blockIdx.x * blockDim.x + threadIdx.x;
    int n = gid >> 5;   // 32 threads/node
    int c = gid & 31;   // 4 outputs each
    if (n >= N) return;
    float x0 = ctrs[2 * n], x1 = ctrs[2 * n + 1];
    float y0 = feats[2 * n], y1 = feats[2 * n + 1];
    int o0 = c * 4;
    float hi[4], hs[4];
#pragma unroll
    for (int j = 0; j < 4; ++j) {
        int o = o0 + j;
        float a = fmaf(x0, inW1[2 * o], fmaf(x1, inW1[2 * o + 1], inb1[o]));
        hi[j] = fmaxf(a, 0.f);
        float b = fmaf(y0, segW1[2 * o], fmaf(y1, segW1[2 * o + 1], segb1[o]));
        hs[j] = fmaxf(b, 0.f);
    }
    *(float4*)&h_in[(size_t)n * D + o0] = make_float4(hi[0], hi[1], hi[2], hi[3]);
    *(float4*)&h_seg[(size_t)n * D + o0] = make_float4(hs[0], hs[1], hs[2], hs[3]);
}

// ---------------------------------------------------------------------------
// out[n][o] = act( sum_k A[n][k]*W[o*ldw+k] (+bias[o]) (+addin[n][o]) )
// ---------------------------------------------------------------------------
template <int BIAS, int RELU, int ADDIN>
__global__ __launch_bounds__(256) void gemm128_kernel(
    const float* __restrict__ A, const float* __restrict__ W,
    const float* __restrict__ bias, const float* addin, float* out, int N,
    int ldw) {
    __shared__ float xs[32][BN + 8];
    __shared__ float wt[32][D + 4];
    int t = threadIdx.x;
    int n0 = blockIdx.x * BN;
    int tn = t >> 4;
    int to = t & 15;
    float acc[8][8];
#pragma unroll
    for (int j = 0; j < 8; ++j)
#pragma unroll
        for (int m = 0; m < 8; ++m) acc[j][m] = 0.f;

    for (int kc = 0; kc < 4; ++kc) {
        int k0 = kc * 32;
#pragma unroll
        for (int i = 0; i < 4; ++i) {
            int f4 = i * 256 + t;
            int row = f4 >> 3;
            int c4 = f4 & 7;
            int n = n0 + row;
            float4 v = make_float4(0.f, 0.f, 0.f, 0.f);
            if (n < N) v = *(const float4*)&A[(size_t)n * D + k0 + c4 * 4];
            xs[c4 * 4 + 0][row] = v.x;
            xs[c4 * 4 + 1][row] = v.y;
            xs[c4 * 4 + 2][row] = v.z;
            xs[c4 * 4 + 3][row] = v.w;
        }
#pragma unroll
        for (int i = 0; i < 4; ++i) {
            int f4 = i * 256 + t;
            int o = f4 >> 3;
            int c4 = f4 & 7;
            float4 v = *(const float4*)&W[(size_t)o * ldw + k0 + c4 * 4];
            wt[c4 * 4 + 0][o] = v.x;
            wt[c4 * 4 + 1][o] = v.y;
            wt[c4 * 4 + 2][o] = v.z;
            wt[c4 * 4 + 3][o] = v.w;
        }
        __syncthreads();
#pragma unroll
        for (int kk = 0; kk < 32; ++kk) {
            float4 xa = *(const float4*)&xs[kk][tn * 8];
            float4 xb = *(const float4*)&xs[kk][tn * 8 + 4];
            float4 wa = *(const float4*)&wt[kk][to * 8];
            float4 wb = *(const float4*)&wt[kk][to * 8 + 4];
            float xr[8] = {xa.x, xa.y, xa.z, xa.w, xb.x, xb.y, xb.z, xb.w};
            float wr[8] = {wa.x, wa.y, wa.z, wa.w, wb.x, wb.y, wb.z, wb.w};
#pragma unroll
            for (int j = 0; j < 8; ++j)
#pragma unroll
                for (int m = 0; m < 8; ++m)
                    acc[j][m] = fmaf(xr[j], wr[m], acc[j][m]);
        }
        __syncthreads();
    }
    int o0 = to * 8;
    float bv[8] = {0, 0, 0, 0, 0, 0, 0, 0};
    if (BIAS) {
        float4 ba = *(const float4*)&bias[o0];
        float4 bb = *(const float4*)&bias[o0 + 4];
        bv[0] = ba.x; bv[1] = ba.y; bv[2] = ba.z; bv[3] = ba.w;
        bv[4] = bb.x; bv[5] = bb.y; bv[6] = bb.z; bv[7] = bb.w;
    }
#pragma unroll
    for (int j = 0; j < 8; ++j) {
        int n = n0 + tn * 8 + j;
        if (n < N) {
            float r[8];
#pragma unroll
            for (int m = 0; m < 8; ++m) r[m] = acc[j][m] + (BIAS ? bv[m] : 0.f);
            if (ADDIN) {
                float4 aa = *(const float4*)&addin[(size_t)n * D + o0];
                float4 ab = *(const float4*)&addin[(size_t)n * D + o0 + 4];
                r[0] += aa.x; r[1] += aa.y; r[2] += aa.z; r[3] += aa.w;
                r[4] += ab.x; r[5] += ab.y; r[6] += ab.z; r[7] += ab.w;
            }
            if (RELU) {
#pragma unroll
                for (int m = 0; m < 8; ++m) r[m] = fmaxf(r[m], 0.f);
            }
            *(float4*)&out[(size_t)n * D + o0] = make_float4(r[0], r[1], r[2], r[3]);
            *(float4*)&out[(size_t)n * D + o0 + 4] = make_float4(r[4], r[5], r[6], r[7]);
        }
    }
}

// ---------------------------------------------------------------------------
// Fallback: temp[u[e]][:] += Y[v[e]][:]  (HW fp32 atomics)
// ---------------------------------------------------------------------------
__global__ void scatter_add_kernel(const float* __restrict__ Y,
                                   const int* __restrict__ eu,
                                   const int* __restrict__ ev, float* temp,
                                   int E) {
    int gid = blockIdx.x * blockDim.x + threadIdx.x;
    int e = gid >> 5;
    int c = gid & 31;
    if (e >= E) return;
    int u = eu[e], v = ev[e];
    float4 m = *(const float4*)&Y[(size_t)v * D + c * 4];
    float* dst = &temp[(size_t)u * D + c * 4];
    unsafeAtomicAdd(dst + 0, m.x);
    unsafeAtomicAdd(dst + 1, m.y);
    unsafeAtomicAdd(dst + 2, m.z);
    unsafeAtomicAdd(dst + 3, m.w);
}

// ---------------------------------------------------------------------------
// CSR build: histogram of deg[t][u]
// ---------------------------------------------------------------------------
__global__ void csr_hist_kernel(const int* __restrict__ edge_u, int* deg,
                                int N, int E) {
    int gid = blockIdx.x * blockDim.x + threadIdx.x;
    if (gid >= NT * E) return;
    int t = gid / E;
    int u = edge_u[gid];
    atomicAdd(&deg[(size_t)t * N + u], 1);
}

// one block (1024 threads) per edge type: exclusive scan deg -> rowptr, cur
__global__ __launch_bounds__(1024) void csr_scan_kernel(
    const int* __restrict__ deg, int* rowptr, int* cur, int N) {
    int t = blockIdx.x;
    int tid = threadIdx.x;
    const int C = (N + 1023) >> 10;
    int base = tid * C;
    int s = 0;
    for (int i = 0; i < C; ++i) {
        int idx = base + i;
        if (idx < N) s += deg[(size_t)t * N + idx];
    }
    __shared__ int ps[1024];
    ps[tid] = s;
    __syncthreads();
    for (int off = 1; off < 1024; off <<= 1) {
        int v = (tid >= off) ? ps[tid - off] : 0;
        __syncthreads();
        ps[tid] += v;
        __syncthreads();
    }
    int run = (tid == 0) ? 0 : ps[tid - 1];
    size_t rb = (size_t)t * (N + 1);
    for (int i = 0; i < C; ++i) {
        int idx = base + i;
        if (idx < N) {
            rowptr[rb + idx] = run;
            cur[rb + idx] = run;
            run += deg[(size_t)t * N + idx];
        }
    }
    if (tid == 1023) rowptr[rb + N] = run;
}

__global__ void csr_fill_kernel(const int* __restrict__ edge_u,
                                const int* __restrict__ edge_v, int* cur,
                                int* col, int N, int E) {
    int gid = blockIdx.x * blockDim.x + threadIdx.x;
    if (gid >= NT * E) return;
    int t = gid / E;
    int u = edge_u[gid];
    int v = edge_v[gid];
    int pos = atomicAdd(&cur[(size_t)t * (N + 1) + u], 1);
    col[(size_t)t * E + pos] = v;
}

// ---------------------------------------------------------------------------
// CSR gather: temp[u] += sum_{k in row(u)} Y[col[k]]   (one wave per node)
// ---------------------------------------------------------------------------
__global__ __launch_bounds__(256) void csr_gather_kernel(
    const float* __restrict__ Y, const int* __restrict__ rowptr,
    const int* __restrict__ col, float* temp, int N) {
    int wid = (int)((blockIdx.x * (size_t)blockDim.x + threadIdx.x) >> 6);
    int lane = threadIdx.x & 63;
    if (wid >= N) return;
    int beg = rowptr[wid];
    int end = rowptr[wid + 1];
    if (beg == end) return;
    size_t ro = (size_t)wid * D + lane * 2;
    float2 acc = *(float2*)&temp[ro];
    for (int k = beg; k < end; ++k) {
        int v = col[k];
        float2 y = *(const float2*)&Y[(size_t)v * D + lane * 2];
        acc.x += y.x;
        acc.y += y.y;
    }
    *(float2*)&temp[ro] = acc;
}

// ---------------------------------------------------------------------------
// in-place GroupNorm(1,D) + affine + relu, one wave per node
// ---------------------------------------------------------------------------
__global__ __launch_bounds__(256) void norm_relu_kernel(float* temp,
                                                        const float* __restrict__ g,
                                                        const float* __restrict__ b,
                                                        int N) {
    int wid = (int)((blockIdx.x * (size_t)blockDim.x + threadIdx.x) >> 6);
    int lane = threadIdx.x & 63;
    if (wid >= N) return;
    float2 x = *(float2*)&temp[(size_t)wid * D + lane * 2];
    float s = x.x + x.y;
    float sq = x.x * x.x + x.y * x.y;
#pragma unroll
    for (int off = 32; off; off >>= 1) {
        s += __shfl_xor(s, off);
        sq += __shfl_xor(sq, off);
    }
    float mu = s * (1.f / 128.f);
    float var = sq * (1.f / 128.f) - mu * mu;
    float rs = rsqrtf(var + 1e-5f);
    float r0 = fmaxf(fmaf((x.x - mu) * rs, g[lane * 2], b[lane * 2]), 0.f);
    float r1 = fmaxf(fmaf((x.y - mu) * rs, g[lane * 2 + 1], b[lane * 2 + 1]), 0.f);
    *(float2*)&temp[(size_t)wid * D + lane * 2] = make_float2(r0, r1);
}

// ---------------------------------------------------------------------------
__global__ void gather_meta_kernel(const int* __restrict__ mark,
                                   const float* __restrict__ embed, float* out,
                                   int N) {
    int gid = blockIdx.x * blockDim.x + threadIdx.x;
    int n = gid >> 5;
    int c = gid & 31;
    if (n >= N) return;
    *(float4*)&out[(size_t)n * D + c * 4] =
        *(const float4*)&embed[(size_t)mark[n] * D + c * 4];
}

// ---------------------------------------------------------------------------
static inline void launch_gemm(const float* A, const float* W, const float* bias,
                               const float* addin, float* out, int N, int ldw,
                               bool relu, hipStream_t s) {
    dim3 grid((N + BN - 1) / BN), blk(256);
    bool B = bias != nullptr, AD = addin != nullptr;
    if (B && !relu && !AD)
        gemm128_kernel<1, 0, 0><<<grid, blk, 0, s>>>(A, W, bias, addin, out, N, ldw);
    else if (B && relu && AD)
        gemm128_kernel<1, 1, 1><<<grid, blk, 0, s>>>(A, W, bias, addin, out, N, ldw);
    else if (!B && !relu && !AD)
        gemm128_kernel<0, 0, 0><<<grid, blk, 0, s>>>(A, W, bias, addin, out, N, ldw);
    else if (B && relu && !AD)
        gemm128_kernel<1, 1, 0><<<grid, blk, 0, s>>>(A, W, bias, addin, out, N, ldw);
    else if (!B && relu && AD)
        gemm128_kernel<0, 1, 1><<<grid, blk, 0, s>>>(A, W, bias, addin, out, N, ldw);
    else if (!B && relu && !AD)
        gemm128_kernel<0, 1, 0><<<grid, blk, 0, s>>>(A, W, bias, addin, out, N, ldw);
    else if (!B && !relu && AD)
        gemm128_kernel<0, 0, 1><<<grid, blk, 0, s>>>(A, W, bias, addin, out, N, ldw);
    else
        gemm128_kernel<1, 0, 1><<<grid, blk, 0, s>>>(A, W, bias, addin, out, N, ldw);
}

extern "C" void kernel_launch(void* const* d_in, const int* in_sizes, int n_in,
                              void* d_out, int out_size, void* d_ws,
                              size_t ws_size, hipStream_t stream) {
    const float* ctrs = (const float*)d_in[0];
    const float* feats = (const float*)d_in[1];
    const float* in_W1 = (const float*)d_in[2];
    const float* in_b1 = (const float*)d_in[3];
    const float* in_W2 = (const float*)d_in[4];
    const float* in_b2 = (const float*)d_in[5];
    const float* seg_W1 = (const float*)d_in[6];
    const float* seg_b1 = (const float*)d_in[7];
    const float* seg_W2 = (const float*)d_in[8];
    const float* seg_b2 = (const float*)d_in[9];
    const float* embed = (const float*)d_in[10];
    const float* meta_W1 = (const float*)d_in[11];
    const float* meta_b1 = (const float*)d_in[12];
    const float* meta_W2 = (const float*)d_in[13];
    const float* meta_b2 = (const float*)d_in[14];
    const float* ctr_W = (const float*)d_in[15];
    const float* edge_W = (const float*)d_in[16];
    const float* norm_g = (const float*)d_in[17];
    const float* norm_b = (const float*)d_in[18];
    const float* ctr2_W1 = (const float*)d_in[19];
    const float* ctr2_b1 = (const float*)d_in[20];
    const float* ctr2_W2 = (const float*)d_in[21];
    const float* ctr2_b2 = (const float*)d_in[22];
    const int* mark_type = (const int*)d_in[23];
    const int* edge_u = (const int*)d_in[24];
    const int* edge_v = (const int*)d_in[25];

    const int N = in_sizes[0] / 2;
    const int E = in_sizes[24] / NT;
    const size_t ND = (size_t)N * D;

    float* F = (float*)d_ws;        // feat / residual
    float* T1 = (float*)d_ws + ND;  // temp
    float* SC = (float*)d_out;      // scratch: Y / hidden / meta

    // persistent CSR arrays in ws after F,T1
    int* rowptr = (int*)((float*)d_ws + 2 * ND);           // NT*(N+1)
    int* col = rowptr + (size_t)NT * (N + 1);              // NT*E
    size_t ws_need = (2 * ND) * sizeof(float) +
                     ((size_t)NT * (N + 1) + (size_t)NT * E) * sizeof(int);
    bool use_csr = (ws_size >= ws_need) &&
                   ((size_t)out_size * sizeof(float) >=
                    ((size_t)NT * N + (size_t)NT * (N + 1)) * sizeof(int));

    dim3 blk(256);
    dim3 g32((N * 32 + 255) / 256);
    dim3 g64(((size_t)N * 64 + 255) / 256);
    dim3 gE((E * 32 + 255) / 256);
    dim3 gTE(((size_t)NT * E + 255) / 256);

    if (use_csr) {
        // build CSR using d_out as scratch for deg + cursor (free until input stage)
        int* deg = (int*)d_out;
        int* cur = deg + (size_t)NT * N;
        hipMemsetAsync(deg, 0, (size_t)NT * N * sizeof(int), stream);
        csr_hist_kernel<<<gTE, blk, 0, stream>>>(edge_u, deg, N, E);
        csr_scan_kernel<<<NT, 1024, 0, stream>>>(deg, rowptr, cur, N);
        csr_fill_kernel<<<gTE, blk, 0, stream>>>(edge_u, edge_v, cur, col, N, E);
    }

    // ---- input stage: feat = relu(mlp(ctrs) + mlp(feats)) ----
    input_hidden_kernel<<<g32, blk, 0, stream>>>(ctrs, feats, in_W1, in_b1,
                                                 seg_W1, seg_b1, T1, SC, N);
    launch_gemm(T1, in_W2, in_b2, nullptr, F, N, D, false, stream);
    launch_gemm(SC, seg_W2, seg_b2, F, F, N, D, true, stream);

    // ---- fuse layers ----
    for (int i = 0; i < NL; ++i) {
        launch_gemm(F, ctr_W + (size_t)i * D * D, nullptr, nullptr, T1, N, D,
                    false, stream);
        for (int t = 0; t < NT; ++t) {
            launch_gemm(F, edge_W + ((size_t)i * NT + t) * D * D, nullptr,
                        nullptr, SC, N, D, false, stream);
            if (use_csr) {
                csr_gather_kernel<<<g64, blk, 0, stream>>>(
                    SC, rowptr + (size_t)t * (N + 1), col + (size_t)t * E, T1, N);
            } else {
                scatter_add_kernel<<<gE, blk, 0, stream>>>(
                    SC, edge_u + (size_t)t * E, edge_v + (size_t)t * E, T1, E);
            }
        }
        norm_relu_kernel<<<g64, blk, 0, stream>>>(T1, norm_g + (size_t)i * D,
                                                  norm_b + (size_t)i * D, N);
        launch_gemm(T1, ctr2_W1 + (size_t)i * D * D, ctr2_b1 + (size_t)i * D,
                    nullptr, SC, N, D, true, stream);
        launch_gemm(SC, ctr2_W2 + (size_t)i * D * D, ctr2_b2 + (size_t)i * D, F,
                    F, N, D, true, stream);
    }

    // ---- meta stage ----
    gather_meta_kernel<<<g32, blk, 0, stream>>>(mark_type, embed, SC, N);
    launch_gemm(F, meta_W1, meta_b1, nullptr, T1, N, 2 * D, false, stream);
    launch_gemm(SC, meta_W1 + D, nullptr, T1, T1, N, 2 * D, true, stream);
    launch_gemm(T1, meta_W2, meta_b2, nullptr, (float*)d_out, N, D, false,
                stream);
}

// Round 3
// 4003.832 us; speedup vs baseline: 3.6900x; 1.6286x over previous
//
#include <hip/hip_runtime.h>

#define D 128
#define NT 10   // edge types
#define NL 4    // layers
#define BN 128  // nodes per gemm block
#define SCH 1024  // nodes per scan chunk

typedef __attribute__((ext_vector_type(8))) short bf16x8;
typedef __attribute__((ext_vector_type(4))) float f32x4;

__device__ inline unsigned short f2bf(float x) {
    union { float f; unsigned u; } v; v.f = x;
    unsigned r = v.u + 0x7FFFu + ((v.u >> 16) & 1u);
    return (unsigned short)(r >> 16);
}
__device__ inline float bf2f(unsigned short h) {
    union { unsigned u; float f; } v; v.u = ((unsigned)h) << 16;
    return v.f;
}

// ---------------------------------------------------------------------------
// h = relu(x @ W1.T + b1) for the two K=2 input MLPs (fused)
// ---------------------------------------------------------------------------
__global__ void input_hidden_kernel(const float* __restrict__ ctrs,
                                    const float* __restrict__ feats,
                                    const float* __restrict__ inW1,
                                    const float* __restrict__ inb1,
                                    const float* __restrict__ segW1,
                                    const float* __restrict__ segb1,
                                    float* __restrict__ h_in,
                                    float* __restrict__ h_seg, int N) {
    int gid = blockIdx.x * blockDim.x + threadIdx.x;
    int n = gid >> 5;
    int c = gid & 31;
    if (n >= N) return;
    float x0 = ctrs[2 * n], x1 = ctrs[2 * n + 1];
    float y0 = feats[2 * n], y1 = feats[2 * n + 1];
    int o0 = c * 4;
    float hi[4], hs[4];
#pragma unroll
    for (int j = 0; j < 4; ++j) {
        int o = o0 + j;
        float a = fmaf(x0, inW1[2 * o], fmaf(x1, inW1[2 * o + 1], inb1[o]));
        hi[j] = fmaxf(a, 0.f);
        float b = fmaf(y0, segW1[2 * o], fmaf(y1, segW1[2 * o + 1], segb1[o]));
        hs[j] = fmaxf(b, 0.f);
    }
    *(float4*)&h_in[(size_t)n * D + o0] = make_float4(hi[0], hi[1], hi[2], hi[3]);
    *(float4*)&h_seg[(size_t)n * D + o0] = make_float4(hs[0], hs[1], hs[2], hs[3]);
}

// ---------------------------------------------------------------------------
// MFMA GEMM: out[n][o] = act( sum_k A[n][k]*W[o*ldw+k] (+bias) (+addin) )
// fp32 in/out; split-bf16 (hi+lo, 3 MFMA terms) for fp32-equivalent precision.
// 128x128 tile, 4 waves, each wave 32 rows x 128 cols (2x8 16x16 frags).
// ---------------------------------------------------------------------------
template <int BIAS, int RELU, int ADDIN>
__global__ __launch_bounds__(256) void gemm_mfma_kernel(
    const float* __restrict__ A, const float* __restrict__ W,
    const float* __restrict__ bias, const float* addin, float* out, int N,
    int ldw) {
    // 40-short rows (80B): 16B-aligned b128 reads, <=2-way bank aliasing
    __shared__ unsigned short a_hi[128][40], a_lo[128][40];
    __shared__ unsigned short w_hi[128][40], w_lo[128][40];
    int t = threadIdx.x;
    int wave = t >> 6, lane = t & 63;
    int fr = lane & 15, fq = lane >> 4;
    int n0 = blockIdx.x * BN;
    f32x4 acc[2][8];
#pragma unroll
    for (int m = 0; m < 2; ++m)
#pragma unroll
        for (int n = 0; n < 8; ++n) acc[m][n] = (f32x4){0.f, 0.f, 0.f, 0.f};

    for (int kc = 0; kc < 4; ++kc) {
        int k0 = kc * 32;
        // stage A chunk 128x32 fp32 -> hi/lo bf16
#pragma unroll
        for (int i = 0; i < 4; ++i) {
            int idx = i * 256 + t;       // float4 index, 8 per row
            int row = idx >> 3, c4 = idx & 7;
            int n = n0 + row;
            float4 v = make_float4(0.f, 0.f, 0.f, 0.f);
            if (n < N) v = *(const float4*)&A[(size_t)n * D + k0 + c4 * 4];
            ushort4 h, l;
            h.x = f2bf(v.x); l.x = f2bf(v.x - bf2f(h.x));
            h.y = f2bf(v.y); l.y = f2bf(v.y - bf2f(h.y));
            h.z = f2bf(v.z); l.z = f2bf(v.z - bf2f(h.z));
            h.w = f2bf(v.w); l.w = f2bf(v.w - bf2f(h.w));
            *(ushort4*)&a_hi[row][c4 * 4] = h;
            *(ushort4*)&a_lo[row][c4 * 4] = l;
        }
        // stage W chunk 128x32 (always full 128 rows)
#pragma unroll
        for (int i = 0; i < 4; ++i) {
            int idx = i * 256 + t;
            int row = idx >> 3, c4 = idx & 7;
            float4 v = *(const float4*)&W[(size_t)row * ldw + k0 + c4 * 4];
            ushort4 h, l;
            h.x = f2bf(v.x); l.x = f2bf(v.x - bf2f(h.x));
            h.y = f2bf(v.y); l.y = f2bf(v.y - bf2f(h.y));
            h.z = f2bf(v.z); l.z = f2bf(v.z - bf2f(h.z));
            h.w = f2bf(v.w); l.w = f2bf(v.w - bf2f(h.w));
            *(ushort4*)&w_hi[row][c4 * 4] = h;
            *(ushort4*)&w_lo[row][c4 * 4] = l;
        }
        __syncthreads();

        bf16x8 ah[2], al[2];
#pragma unroll
        for (int m = 0; m < 2; ++m) {
            int row = wave * 32 + m * 16 + fr;
            ah[m] = *(const bf16x8*)&a_hi[row][fq * 8];
            al[m] = *(const bf16x8*)&a_lo[row][fq * 8];
        }
#pragma unroll
        for (int n = 0; n < 8; ++n) {
            int wr = n * 16 + fr;
            bf16x8 wh = *(const bf16x8*)&w_hi[wr][fq * 8];
            bf16x8 wl = *(const bf16x8*)&w_lo[wr][fq * 8];
#pragma unroll
            for (int m = 0; m < 2; ++m) {
                acc[m][n] = __builtin_amdgcn_mfma_f32_16x16x32_bf16(
                    ah[m], wh, acc[m][n], 0, 0, 0);
                acc[m][n] = __builtin_amdgcn_mfma_f32_16x16x32_bf16(
                    ah[m], wl, acc[m][n], 0, 0, 0);
                acc[m][n] = __builtin_amdgcn_mfma_f32_16x16x32_bf16(
                    al[m], wh, acc[m][n], 0, 0, 0);
            }
        }
        __syncthreads();
    }
    // epilogue: D row=(lane>>4)*4+reg, col=lane&15  [m89-verified mapping]
#pragma unroll
    for (int m = 0; m < 2; ++m) {
#pragma unroll
        for (int j = 0; j < 4; ++j) {
            int row = n0 + wave * 32 + m * 16 + fq * 4 + j;
            if (row < N) {
#pragma unroll
                for (int n = 0; n < 8; ++n) {
                    int col = n * 16 + fr;
                    float r = acc[m][n][j];
                    if (BIAS) r += bias[col];
                    if (ADDIN) r += addin[(size_t)row * D + col];
                    if (RELU) r = fmaxf(r, 0.f);
                    out[(size_t)row * D + col] = r;
                }
            }
        }
    }
}

// ---------------------------------------------------------------------------
// Fallback: temp[u[e]][:] += Y[v[e]][:]  (HW fp32 atomics)
// ---------------------------------------------------------------------------
__global__ void scatter_add_kernel(const float* __restrict__ Y,
                                   const int* __restrict__ eu,
                                   const int* __restrict__ ev, float* temp,
                                   int E) {
    int gid = blockIdx.x * blockDim.x + threadIdx.x;
    int e = gid >> 5;
    int c = gid & 31;
    if (e >= E) return;
    int u = eu[e], v = ev[e];
    float4 m = *(const float4*)&Y[(size_t)v * D + c * 4];
    float* dst = &temp[(size_t)u * D + c * 4];
    unsafeAtomicAdd(dst + 0, m.x);
    unsafeAtomicAdd(dst + 1, m.y);
    unsafeAtomicAdd(dst + 2, m.z);
    unsafeAtomicAdd(dst + 3, m.w);
}

// ---------------------------------------------------------------------------
// CSR build: histogram, hierarchical scan, fill
// ---------------------------------------------------------------------------
__global__ void csr_hist_kernel(const int* __restrict__ edge_u, int* deg,
                                int N, int E) {
    int gid = blockIdx.x * blockDim.x + threadIdx.x;
    if (gid >= NT * E) return;
    int t = gid / E;
    int u = edge_u[gid];
    atomicAdd(&deg[(size_t)t * N + u], 1);
}

__global__ __launch_bounds__(256) void csr_chunksum_kernel(
    const int* __restrict__ deg, int* csum, int N, int nch) {
    int b = blockIdx.x;
    int t = b / nch, ch = b % nch;
    int tid = threadIdx.x;
    const int* dg = deg + (size_t)t * N;
    int base = ch * SCH + tid * 4;
    int s = 0;
#pragma unroll
    for (int j = 0; j < 4; ++j) {
        int idx = base + j;
        if (idx < N) s += dg[idx];
    }
#pragma unroll
    for (int off = 32; off; off >>= 1) s += __shfl_down(s, off);
    __shared__ int wsum[4];
    if ((tid & 63) == 0) wsum[tid >> 6] = s;
    __syncthreads();
    if (tid == 0) csum[b] = wsum[0] + wsum[1] + wsum[2] + wsum[3];
}

__global__ void csr_chunkscan_kernel(int* csum, int* rowptr, int N, int nch) {
    int t = threadIdx.x;
    if (t >= NT) return;
    int run = 0;
    for (int i = 0; i < nch; ++i) {
        int v = csum[t * nch + i];
        csum[t * nch + i] = run;
        run += v;
    }
    rowptr[(size_t)t * (N + 1) + N] = run;
}

__global__ __launch_bounds__(256) void csr_blockscan_kernel(
    const int* __restrict__ deg, const int* __restrict__ csum, int* rowptr,
    int* cur, int N, int nch) {
    int b = blockIdx.x;
    int t = b / nch, ch = b % nch;
    int tid = threadIdx.x;
    const int* dg = deg + (size_t)t * N;
    int base = ch * SCH + tid * 4;
    int d[4];
    int s = 0;
#pragma unroll
    for (int j = 0; j < 4; ++j) {
        int idx = base + j;
        d[j] = (idx < N) ? dg[idx] : 0;
        s += d[j];
    }
    __shared__ int ps[256];
    ps[tid] = s;
    __syncthreads();
    for (int off = 1; off < 256; off <<= 1) {
        int v = (tid >= off) ? ps[tid - off] : 0;
        __syncthreads();
        ps[tid] += v;
        __syncthreads();
    }
    int excl = (tid ? ps[tid - 1] : 0) + csum[b];
    size_t rb = (size_t)t * (N + 1);
#pragma unroll
    for (int j = 0; j < 4; ++j) {
        int idx = base + j;
        if (idx < N) {
            rowptr[rb + idx] = excl;
            cur[rb + idx] = excl;
            excl += d[j];
        }
    }
}

__global__ void csr_fill_kernel(const int* __restrict__ edge_u,
                                const int* __restrict__ edge_v, int* cur,
                                int* col, int N, int E) {
    int gid = blockIdx.x * blockDim.x + threadIdx.x;
    if (gid >= NT * E) return;
    int t = gid / E;
    int u = edge_u[gid];
    int v = edge_v[gid];
    int pos = atomicAdd(&cur[(size_t)t * (N + 1) + u], 1);
    col[(size_t)t * E + pos] = v;
}

// ---------------------------------------------------------------------------
// CSR gather: temp[u] += sum_{k in row(u)} Y[col[k]]   (one wave per node)
// ---------------------------------------------------------------------------
__global__ __launch_bounds__(256) void csr_gather_kernel(
    const float* __restrict__ Y, const int* __restrict__ rowptr,
    const int* __restrict__ col, float* temp, int N) {
    int wid = (int)((blockIdx.x * (size_t)blockDim.x + threadIdx.x) >> 6);
    int lane = threadIdx.x & 63;
    if (wid >= N) return;
    int beg = rowptr[wid];
    int end = rowptr[wid + 1];
    if (beg == end) return;
    size_t ro = (size_t)wid * D + lane * 2;
    float2 acc = *(float2*)&temp[ro];
    for (int k = beg; k < end; ++k) {
        int v = col[k];
        float2 y = *(const float2*)&Y[(size_t)v * D + lane * 2];
        acc.x += y.x;
        acc.y += y.y;
    }
    *(float2*)&temp[ro] = acc;
}

// ---------------------------------------------------------------------------
// in-place GroupNorm(1,D) + affine + relu, one wave per node
// ---------------------------------------------------------------------------
__global__ __launch_bounds__(256) void norm_relu_kernel(float* temp,
                                                        const float* __restrict__ g,
                                                        const float* __restrict__ b,
                                                        int N) {
    int wid = (int)((blockIdx.x * (size_t)blockDim.x + threadIdx.x) >> 6);
    int lane = threadIdx.x & 63;
    if (wid >= N) return;
    float2 x = *(float2*)&temp[(size_t)wid * D + lane * 2];
    float s = x.x + x.y;
    float sq = x.x * x.x + x.y * x.y;
#pragma unroll
    for (int off = 32; off; off >>= 1) {
        s += __shfl_xor(s, off);
        sq += __shfl_xor(sq, off);
    }
    float mu = s * (1.f / 128.f);
    float var = sq * (1.f / 128.f) - mu * mu;
    float rs = rsqrtf(var + 1e-5f);
    float r0 = fmaxf(fmaf((x.x - mu) * rs, g[lane * 2], b[lane * 2]), 0.f);
    float r1 = fmaxf(fmaf((x.y - mu) * rs, g[lane * 2 + 1], b[lane * 2 + 1]), 0.f);
    *(float2*)&temp[(size_t)wid * D + lane * 2] = make_float2(r0, r1);
}

// ---------------------------------------------------------------------------
__global__ void gather_meta_kernel(const int* __restrict__ mark,
                                   const float* __restrict__ embed, float* out,
                                   int N) {
    int gid = blockIdx.x * blockDim.x + threadIdx.x;
    int n = gid >> 5;
    int c = gid & 31;
    if (n >= N) return;
    *(float4*)&out[(size_t)n * D + c * 4] =
        *(const float4*)&embed[(size_t)mark[n] * D + c * 4];
}

// ---------------------------------------------------------------------------
static inline void launch_gemm(const float* A, const float* W, const float* bias,
                               const float* addin, float* out, int N, int ldw,
                               bool relu, hipStream_t s) {
    dim3 grid((N + BN - 1) / BN), blk(256);
    bool B = bias != nullptr, AD = addin != nullptr;
    if (B && !relu && !AD)
        gemm_mfma_kernel<1, 0, 0><<<grid, blk, 0, s>>>(A, W, bias, addin, out, N, ldw);
    else if (B && relu && AD)
        gemm_mfma_kernel<1, 1, 1><<<grid, blk, 0, s>>>(A, W, bias, addin, out, N, ldw);
    else if (!B && !relu && !AD)
        gemm_mfma_kernel<0, 0, 0><<<grid, blk, 0, s>>>(A, W, bias, addin, out, N, ldw);
    else if (B && relu && !AD)
        gemm_mfma_kernel<1, 1, 0><<<grid, blk, 0, s>>>(A, W, bias, addin, out, N, ldw);
    else if (!B && relu && AD)
        gemm_mfma_kernel<0, 1, 1><<<grid, blk, 0, s>>>(A, W, bias, addin, out, N, ldw);
    else if (!B && relu && !AD)
        gemm_mfma_kernel<0, 1, 0><<<grid, blk, 0, s>>>(A, W, bias, addin, out, N, ldw);
    else if (!B && !relu && AD)
        gemm_mfma_kernel<0, 0, 1><<<grid, blk, 0, s>>>(A, W, bias, addin, out, N, ldw);
    else
        gemm_mfma_kernel<1, 0, 1><<<grid, blk, 0, s>>>(A, W, bias, addin, out, N, ldw);
}

extern "C" void kernel_launch(void* const* d_in, const int* in_sizes, int n_in,
                              void* d_out, int out_size, void* d_ws,
                              size_t ws_size, hipStream_t stream) {
    const float* ctrs = (const float*)d_in[0];
    const float* feats = (const float*)d_in[1];
    const float* in_W1 = (const float*)d_in[2];
    const float* in_b1 = (const float*)d_in[3];
    const float* in_W2 = (const float*)d_in[4];
    const float* in_b2 = (const float*)d_in[5];
    const float* seg_W1 = (const float*)d_in[6];
    const float* seg_b1 = (const float*)d_in[7];
    const float* seg_W2 = (const float*)d_in[8];
    const float* seg_b2 = (const float*)d_in[9];
    const float* embed = (const float*)d_in[10];
    const float* meta_W1 = (const float*)d_in[11];
    const float* meta_b1 = (const float*)d_in[12];
    const float* meta_W2 = (const float*)d_in[13];
    const float* meta_b2 = (const float*)d_in[14];
    const float* ctr_W = (const float*)d_in[15];
    const float* edge_W = (const float*)d_in[16];
    const float* norm_g = (const float*)d_in[17];
    const float* norm_b = (const float*)d_in[18];
    const float* ctr2_W1 = (const float*)d_in[19];
    const float* ctr2_b1 = (const float*)d_in[20];
    const float* ctr2_W2 = (const float*)d_in[21];
    const float* ctr2_b2 = (const float*)d_in[22];
    const int* mark_type = (const int*)d_in[23];
    const int* edge_u = (const int*)d_in[24];
    const int* edge_v = (const int*)d_in[25];

    const int N = in_sizes[0] / 2;
    const int E = in_sizes[24] / NT;
    const size_t ND = (size_t)N * D;
    const int nch = (N + SCH - 1) / SCH;

    float* F = (float*)d_ws;        // feat / residual
    float* T1 = (float*)d_ws + ND;  // temp
    float* SC = (float*)d_out;      // scratch: Y / hidden / meta

    // persistent CSR arrays in ws after F,T1
    int* rowptr = (int*)((float*)d_ws + 2 * ND);  // NT*(N+1)
    int* col = rowptr + (size_t)NT * (N + 1);     // NT*E
    size_t ws_need = (2 * ND) * sizeof(float) +
                     ((size_t)NT * (N + 1) + (size_t)NT * E) * sizeof(int);
    size_t out_need = ((size_t)NT * N + (size_t)NT * (N + 1) +
                       2 * (size_t)NT * nch) * sizeof(int);
    bool use_csr = (ws_size >= ws_need) &&
                   ((size_t)out_size * sizeof(float) >= out_need);

    dim3 blk(256);
    dim3 g32((N * 32 + 255) / 256);
    dim3 g64(((size_t)N * 64 + 255) / 256);
    dim3 gE((E * 32 + 255) / 256);
    dim3 gTE(((size_t)NT * E + 255) / 256);

    if (use_csr) {
        // build CSR; d_out is free scratch until input stage
        int* deg = (int*)d_out;                  // NT*N
        int* cur = deg + (size_t)NT * N;         // NT*(N+1)
        int* csum = cur + (size_t)NT * (N + 1);  // NT*nch
        hipMemsetAsync(deg, 0, (size_t)NT * N * sizeof(int), stream);
        csr_hist_kernel<<<gTE, blk, 0, stream>>>(edge_u, deg, N, E);
        csr_chunksum_kernel<<<NT * nch, blk, 0, stream>>>(deg, csum, N, nch);
        csr_chunkscan_kernel<<<1, 64, 0, stream>>>(csum, rowptr, N, nch);
        csr_blockscan_kernel<<<NT * nch, blk, 0, stream>>>(deg, csum, rowptr,
                                                           cur, N, nch);
        csr_fill_kernel<<<gTE, blk, 0, stream>>>(edge_u, edge_v, cur, col, N, E);
    }

    // ---- input stage: feat = relu(mlp(ctrs) + mlp(feats)) ----
    input_hidden_kernel<<<g32, blk, 0, stream>>>(ctrs, feats, in_W1, in_b1,
                                                 seg_W1, seg_b1, T1, SC, N);
    launch_gemm(T1, in_W2, in_b2, nullptr, F, N, D, false, stream);
    launch_gemm(SC, seg_W2, seg_b2, F, F, N, D, true, stream);

    // ---- fuse layers ----
    for (int i = 0; i < NL; ++i) {
        launch_gemm(F, ctr_W + (size_t)i * D * D, nullptr, nullptr, T1, N, D,
                    false, stream);
        for (int t = 0; t < NT; ++t) {
            launch_gemm(F, edge_W + ((size_t)i * NT + t) * D * D, nullptr,
                        nullptr, SC, N, D, false, stream);
            if (use_csr) {
                csr_gather_kernel<<<g64, blk, 0, stream>>>(
                    SC, rowptr + (size_t)t * (N + 1), col + (size_t)t * E, T1, N);
            } else {
                scatter_add_kernel<<<gE, blk, 0, stream>>>(
                    SC, edge_u + (size_t)t * E, edge_v + (size_t)t * E, T1, E);
            }
        }
        norm_relu_kernel<<<g64, blk, 0, stream>>>(T1, norm_g + (size_t)i * D,
                                                  norm_b + (size_t)i * D, N);
        launch_gemm(T1, ctr2_W1 + (size_t)i * D * D, ctr2_b1 + (size_t)i * D,
                    nullptr, SC, N, D, true, stream);
        launch_gemm(SC, ctr2_W2 + (size_t)i * D * D, ctr2_b2 + (size_t)i * D, F,
                    F, N, D, true, stream);
    }

    // ---- meta stage ----
    gather_meta_kernel<<<g32, blk, 0, stream>>>(mark_type, embed, SC, N);
    launch_gemm(F, meta_W1, meta_b1, nullptr, T1, N, 2 * D, false, stream);
    launch_gemm(SC, meta_W1 + D, nullptr, T1, T1, N, 2 * D, true, stream);
    launch_gemm(T1, meta_W2, meta_b2, nullptr, (float*)d_out, N, D, false,
                stream);
}